// Round 1
// baseline (795.299 us; speedup 1.0000x reference)
//
#include <hip/hip_runtime.h>

// Router: logits = x @ W^T, softmax -> argmax one-hot + top prob + logits.
// x: [65536, 2048] fp32, W: [64, 2048] fp32.
// Out (flat float): onehot [T*64] | top_prob [T] | logits [T*64].

constexpr int T_TOK = 65536;
constexpr int DM    = 2048;
constexpr int NE    = 64;
constexpr int BM    = 128;   // tokens per block
constexpr int BK    = 64;    // k-chunk
constexpr int PR    = 68;    // padded LDS row (floats): 68*4=272B, 16B aligned

__global__ __launch_bounds__(256, 2)
void router_kernel(const float* __restrict__ x, const float* __restrict__ W,
                   float* __restrict__ onehot, float* __restrict__ topp,
                   float* __restrict__ logits)
{
    __shared__ float xs[BM][PR];   // token-major x tile: xs[token][k]
    __shared__ float ws[BK][PR];   // k-major transposed W tile: ws[k][expert]

    const int tid = threadIdx.x;
    const int tx  = tid & 15;      // expert group: experts tx*4 .. tx*4+3
    const int ty  = tid >> 4;      // 0..15; tokens ty + 16*i, i=0..7
    const long t0 = (long)blockIdx.x * BM;

    float acc[8][4];
#pragma unroll
    for (int i = 0; i < 8; ++i)
#pragma unroll
        for (int j = 0; j < 4; ++j) acc[i][j] = 0.0f;

    const int s_tok = tid >> 4;        // staging: token/expert within pass
    const int s_k   = (tid & 15) * 4;  // staging: float4 offset in k-chunk

    for (int kc = 0; kc < DM; kc += BK) {
        if (kc) __syncthreads();   // previous compute must finish before overwrite

        // stage x tile: 128 tokens x 64 k, coalesced 16B loads
#pragma unroll
        for (int p = 0; p < 8; ++p) {
            const int t = p * 16 + s_tok;
            const float4 v = *(const float4*)(x + (t0 + t) * DM + kc + s_k);
            *(float4*)(&xs[t][s_k]) = v;
        }
        // stage W tile transposed to k-major
#pragma unroll
        for (int p = 0; p < 4; ++p) {
            const int e = p * 16 + s_tok;
            const float4 v = *(const float4*)(W + (long)e * DM + kc + s_k);
            ws[s_k + 0][e] = v.x;
            ws[s_k + 1][e] = v.y;
            ws[s_k + 2][e] = v.z;
            ws[s_k + 3][e] = v.w;
        }
        __syncthreads();

#pragma unroll
        for (int kk = 0; kk < BK; kk += 4) {
            float wv[4][4];   // wv[dk][j] = W[expert tx*4+j][kc+kk+dk]
#pragma unroll
            for (int dk = 0; dk < 4; ++dk)
                *(float4*)wv[dk] = *(const float4*)(&ws[kk + dk][tx * 4]);
#pragma unroll
            for (int i = 0; i < 8; ++i) {
                const float4 xv = *(const float4*)(&xs[ty + 16 * i][kk]);
                float xa[4] = {xv.x, xv.y, xv.z, xv.w};
#pragma unroll
                for (int j = 0; j < 4; ++j) {
#pragma unroll
                    for (int dk = 0; dk < 4; ++dk)
                        acc[i][j] = fmaf(xa[dk], wv[dk][j], acc[i][j]);
                }
            }
        }
    }

    // Epilogue: per token row of 64 logits held by 16 lanes (same ty).
#pragma unroll
    for (int i = 0; i < 8; ++i) {
        const long tok = t0 + ty + 16 * i;

        // local max + argmax (first occurrence => strict >)
        float m  = acc[i][0];
        int   mi = tx * 4;
#pragma unroll
        for (int j = 1; j < 4; ++j) {
            if (acc[i][j] > m) { m = acc[i][j]; mi = tx * 4 + j; }
        }
        // reduce across the 16 lanes sharing this token (lane bits 0..3 = tx)
#pragma unroll
        for (int d = 1; d < 16; d <<= 1) {
            const float om  = __shfl_xor(m, d, 64);
            const int   omi = __shfl_xor(mi, d, 64);
            if (om > m || (om == m && omi < mi)) { m = om; mi = omi; }
        }
        // sum of exp(l - max)
        float s = 0.0f;
#pragma unroll
        for (int j = 0; j < 4; ++j) s += __expf(acc[i][j] - m);
#pragma unroll
        for (int d = 1; d < 16; d <<= 1) s += __shfl_xor(s, d, 64);

        float4 oh, lg;
        oh.x = (tx * 4 + 0 == mi) ? 1.0f : 0.0f;
        oh.y = (tx * 4 + 1 == mi) ? 1.0f : 0.0f;
        oh.z = (tx * 4 + 2 == mi) ? 1.0f : 0.0f;
        oh.w = (tx * 4 + 3 == mi) ? 1.0f : 0.0f;
        lg.x = acc[i][0]; lg.y = acc[i][1]; lg.z = acc[i][2]; lg.w = acc[i][3];

        *(float4*)(onehot + tok * NE + tx * 4) = oh;
        *(float4*)(logits + tok * NE + tx * 4) = lg;
        if (tx == 0) topp[tok] = 1.0f / s;   // exp(m-m)/sum = 1/s
    }
}

extern "C" void kernel_launch(void* const* d_in, const int* in_sizes, int n_in,
                              void* d_out, int out_size, void* d_ws, size_t ws_size,
                              hipStream_t stream)
{
    const float* x = (const float*)d_in[0];
    const float* W = (const float*)d_in[1];
    float* out = (float*)d_out;

    float* onehot = out;                               // [T*64]
    float* topp   = out + (long)T_TOK * NE;            // [T]
    float* logits = topp + T_TOK;                      // [T*64]

    router_kernel<<<dim3(T_TOK / BM), dim3(256), 0, stream>>>(x, W, onehot, topp, logits);
}

// Round 2
// 729.125 us; speedup vs baseline: 1.0908x; 1.0908x over previous
//
#include <hip/hip_runtime.h>

// Router: logits = x @ W^T (fp32-exact via 3-way bf16 split + 6 MFMA passes),
// softmax -> argmax one-hot + top prob + logits.
// x: [65536, 2048] fp32, W: [64, 2048] fp32.
// Out (flat float): onehot [T*64] | top_prob [T] | logits [T*64].

constexpr int T_TOK = 65536;
constexpr int DM    = 2048;
constexpr int NE    = 64;
constexpr int BM    = 128;            // tokens per block (4 waves x 32)
constexpr int BK    = 64;             // k chunk
constexpr int NCH   = DM / BK;        // 32
constexpr int WPAD  = 72;             // bf16 row stride for W planes (144 B -> balanced banks)
constexpr int PLANE = NE * WPAD;      // 4608 bf16 per plane
constexpr int WBUF  = 3 * PLANE;      // one k-chunk: 3 planes (h,m,l)

typedef __attribute__((ext_vector_type(8))) short bf16x8;
typedef __attribute__((ext_vector_type(4))) float f32x4;

// Exact truncating split of fp32 into 3 bf16 planes: x == h + m + l (bitwise exact:
// 24 mantissa bits = 3 x 8; residuals always fit 8 significant bits; bf16 exponent
// range == fp32 so no denormal loss for |x| >= 2^-100).
__device__ __forceinline__ void split3(const f32x4& a, const f32x4& b,
                                       bf16x8& h, bf16x8& m, bf16x8& l) {
#pragma unroll
    for (int j = 0; j < 8; ++j) {
        const float xv = (j < 4) ? a[j] : b[j - 4];
        const unsigned u0 = __float_as_uint(xv);
        h[j] = (short)(u0 >> 16);
        const float r1 = xv - __uint_as_float(u0 & 0xFFFF0000u);
        const unsigned u1 = __float_as_uint(r1);
        m[j] = (short)(u1 >> 16);
        const float r2 = r1 - __uint_as_float(u1 & 0xFFFF0000u);
        l[j] = (short)(__float_as_uint(r2) >> 16);
    }
}

__global__ __launch_bounds__(256, 2)
void router_mfma(const float* __restrict__ x, const float* __restrict__ W,
                 float* __restrict__ onehot, float* __restrict__ topp,
                 float* __restrict__ logits)
{
    __shared__ __align__(16) unsigned short wlds[2 * WBUF];  // double-buffered W planes

    const int tid  = threadIdx.x;
    const int lane = tid & 63;
    const int wave = tid >> 6;
    const int r16  = lane & 15;     // MFMA m/n lane index
    const int quad = lane >> 4;     // MFMA k-group / row-group

    const long blk_t0 = (long)blockIdx.x * BM;
    const long trow0  = blk_t0 + wave * 32 + r16;   // mt=0 token row
    const long trow1  = trow0 + 16;                  // mt=1

    const float* xp0 = x + trow0 * DM + quad * 8;
    const float* xp1 = x + trow1 * DM + quad * 8;

    // W staging: thread covers W[e=tid>>2][k0=(tid&3)*16 .. +16] per chunk
    const int we  = tid >> 2;
    const int wk0 = (tid & 3) * 16;
    const float* wp = W + (long)we * DM + wk0;
    const int wo = we * WPAD + wk0;   // LDS bf16 offset within a plane

    f32x4 acc[2][4];
#pragma unroll
    for (int mt = 0; mt < 2; ++mt)
#pragma unroll
        for (int nt = 0; nt < 4; ++nt) acc[mt][nt] = (f32x4){0.f, 0.f, 0.f, 0.f};

    f32x4 xn[2][2][2];   // prefetch regs [mt][ks][2xfloat4]
    f32x4 wn[4];
    bf16x8 af[2][2][3];  // A fragments [mt][ks][plane]

    // ---- preload chunk 0
#pragma unroll
    for (int mt = 0; mt < 2; ++mt)
#pragma unroll
        for (int ks = 0; ks < 2; ++ks) {
            const float* p = (mt ? xp1 : xp0) + ks * 32;
            xn[mt][ks][0] = *(const f32x4*)p;
            xn[mt][ks][1] = *(const f32x4*)(p + 4);
        }
#pragma unroll
    for (int j = 0; j < 4; ++j) wn[j] = *(const f32x4*)(wp + j * 4);

#pragma unroll
    for (int mt = 0; mt < 2; ++mt)
#pragma unroll
        for (int ks = 0; ks < 2; ++ks)
            split3(xn[mt][ks][0], xn[mt][ks][1],
                   af[mt][ks][0], af[mt][ks][1], af[mt][ks][2]);
    {
        bf16x8 h0, m0, l0, h1, m1, l1;
        split3(wn[0], wn[1], h0, m0, l0);
        split3(wn[2], wn[3], h1, m1, l1);
        unsigned short* wb = wlds;  // buffer 0
        *(bf16x8*)(wb + 0 * PLANE + wo)     = h0;
        *(bf16x8*)(wb + 0 * PLANE + wo + 8) = h1;
        *(bf16x8*)(wb + 1 * PLANE + wo)     = m0;
        *(bf16x8*)(wb + 1 * PLANE + wo + 8) = m1;
        *(bf16x8*)(wb + 2 * PLANE + wo)     = l0;
        *(bf16x8*)(wb + 2 * PLANE + wo + 8) = l1;
    }
    __syncthreads();

    for (int kc = 0; kc < NCH; ++kc) {
        const int nxt = kc + 1;
        if (nxt < NCH) {
            // issue prefetch loads for next chunk (consumed after the MFMAs)
#pragma unroll
            for (int mt = 0; mt < 2; ++mt)
#pragma unroll
                for (int ks = 0; ks < 2; ++ks) {
                    const float* p = (mt ? xp1 : xp0) + nxt * BK + ks * 32;
                    xn[mt][ks][0] = *(const f32x4*)p;
                    xn[mt][ks][1] = *(const f32x4*)(p + 4);
                }
#pragma unroll
            for (int j = 0; j < 4; ++j) wn[j] = *(const f32x4*)(wp + nxt * BK + j * 4);
        }

        // ---- 96 MFMAs on current chunk; B frags from LDS buffer (kc&1)
        const unsigned short* wb = wlds + (kc & 1) * WBUF;
        const int bo = r16 * WPAD + quad * 8;
#pragma unroll
        for (int ks = 0; ks < 2; ++ks) {
#pragma unroll
            for (int nt = 0; nt < 4; ++nt) {
                const int eo = (nt * 16) * WPAD + bo + ks * 32;
                const bf16x8 bh = *(const bf16x8*)(wb + 0 * PLANE + eo);
                const bf16x8 bm = *(const bf16x8*)(wb + 1 * PLANE + eo);
                const bf16x8 bl = *(const bf16x8*)(wb + 2 * PLANE + eo);
#pragma unroll
                for (int mt = 0; mt < 2; ++mt) {
                    f32x4 c = acc[mt][nt];
                    c = __builtin_amdgcn_mfma_f32_16x16x32_bf16(af[mt][ks][0], bh, c, 0, 0, 0);
                    c = __builtin_amdgcn_mfma_f32_16x16x32_bf16(af[mt][ks][1], bh, c, 0, 0, 0);
                    c = __builtin_amdgcn_mfma_f32_16x16x32_bf16(af[mt][ks][2], bh, c, 0, 0, 0);
                    c = __builtin_amdgcn_mfma_f32_16x16x32_bf16(af[mt][ks][0], bm, c, 0, 0, 0);
                    c = __builtin_amdgcn_mfma_f32_16x16x32_bf16(af[mt][ks][1], bm, c, 0, 0, 0);
                    c = __builtin_amdgcn_mfma_f32_16x16x32_bf16(af[mt][ks][0], bl, c, 0, 0, 0);
                    acc[mt][nt] = c;
                }
            }
        }

        if (nxt < NCH) {
            // convert prefetched data; write W planes to the other LDS buffer
#pragma unroll
            for (int mt = 0; mt < 2; ++mt)
#pragma unroll
                for (int ks = 0; ks < 2; ++ks)
                    split3(xn[mt][ks][0], xn[mt][ks][1],
                           af[mt][ks][0], af[mt][ks][1], af[mt][ks][2]);
            bf16x8 h0, m0, l0, h1, m1, l1;
            split3(wn[0], wn[1], h0, m0, l0);
            split3(wn[2], wn[3], h1, m1, l1);
            unsigned short* wb2 = wlds + (nxt & 1) * WBUF;
            *(bf16x8*)(wb2 + 0 * PLANE + wo)     = h0;
            *(bf16x8*)(wb2 + 0 * PLANE + wo + 8) = h1;
            *(bf16x8*)(wb2 + 1 * PLANE + wo)     = m0;
            *(bf16x8*)(wb2 + 1 * PLANE + wo + 8) = m1;
            *(bf16x8*)(wb2 + 2 * PLANE + wo)     = l0;
            *(bf16x8*)(wb2 + 2 * PLANE + wo + 8) = l1;
        }
        __syncthreads();
    }

    // ---- epilogue: C layout col=lane&15 (expert), row=quad*4+reg (token)
#pragma unroll
    for (int mt = 0; mt < 2; ++mt) {
#pragma unroll
        for (int reg = 0; reg < 4; ++reg) {
            const long t = blk_t0 + wave * 32 + mt * 16 + quad * 4 + reg;

            float mval = acc[mt][0][reg];
            int   mi   = r16;
#pragma unroll
            for (int nt = 1; nt < 4; ++nt) {
                const float v = acc[mt][nt][reg];
                if (v > mval) { mval = v; mi = nt * 16 + r16; }  // e ascending in nt
            }
#pragma unroll
            for (int d = 1; d < 16; d <<= 1) {
                const float om = __shfl_xor(mval, d, 64);
                const int   oi = __shfl_xor(mi, d, 64);
                if (om > mval || (om == mval && oi < mi)) { mval = om; mi = oi; }
            }
            float s = 0.f;
#pragma unroll
            for (int nt = 0; nt < 4; ++nt) s += __expf(acc[mt][nt][reg] - mval);
#pragma unroll
            for (int d = 1; d < 16; d <<= 1) s += __shfl_xor(s, d, 64);

            const long ob = t * NE + r16;
#pragma unroll
            for (int nt = 0; nt < 4; ++nt) {
                logits[ob + nt * 16] = acc[mt][nt][reg];
                onehot[ob + nt * 16] = (nt * 16 + r16 == mi) ? 1.0f : 0.0f;
            }
            if (r16 == 0) topp[t] = 1.0f / s;
        }
    }
}

extern "C" void kernel_launch(void* const* d_in, const int* in_sizes, int n_in,
                              void* d_out, int out_size, void* d_ws, size_t ws_size,
                              hipStream_t stream)
{
    const float* x = (const float*)d_in[0];
    const float* W = (const float*)d_in[1];
    float* out = (float*)d_out;

    float* onehot = out;                     // [T*64]
    float* topp   = out + (long)T_TOK * NE;  // [T]
    float* logits = topp + T_TOK;            // [T*64]

    router_mfma<<<dim3(T_TOK / BM), dim3(256), 0, stream>>>(x, W, onehot, topp, logits);
}